// Round 1
// baseline (314.053 us; speedup 1.0000x reference)
//
#include <hip/hip_runtime.h>
#include <math.h>

#define D_MODEL 1024
#define N_HEADS 16
#define HEAD_DIM 64
#define SEQ_T 2048
#define BATCH 2

typedef __attribute__((ext_vector_type(8))) short short8;
typedef __attribute__((ext_vector_type(4))) float f32x4;

__device__ __forceinline__ unsigned short f2bf(float f) {
    union { float f; unsigned int u; } v; v.f = f;
    return (unsigned short)((v.u + 0x7FFFu + ((v.u >> 16) & 1u)) >> 16);
}

// ---------------- fp32 -> bf16 convert ----------------
__global__ void cvt_bf16(const float* __restrict__ in, unsigned short* __restrict__ out, int n4) {
    int i = blockIdx.x * blockDim.x + threadIdx.x;
    if (i >= n4) return;
    float4 v = ((const float4*)in)[i];
    ushort4 o;
    o.x = f2bf(v.x); o.y = f2bf(v.y); o.z = f2bf(v.z); o.w = f2bf(v.w);
    ((ushort4*)out)[i] = o;
}

// ---------------- C = A[M,K] * W[N,K]^T + bias ----------------
// MODE 0: bf16 out at [B,H,T,Dh]   (q / k)
// MODE 1: bf16 out at [B,H,Dh,T]   (v transposed)
// MODE 2: fp32 out row-major [M,N] (final projection)
template<int MODE>
__global__ __launch_bounds__(256, 2) void gemm_bt(
    const unsigned short* __restrict__ A,
    const unsigned short* __restrict__ W,
    const float* __restrict__ bias,
    void* __restrict__ outp)
{
    constexpr int N = 1024, K = 1024, LDSW = 40; // 32 + 8 pad
    __shared__ unsigned short As[128 * LDSW];
    __shared__ unsigned short Bs[128 * LDSW];
    const int m0 = blockIdx.y * 128;
    const int n0 = blockIdx.x * 128;
    const int tid = threadIdx.x;
    const int w = tid >> 6, lane = tid & 63;
    const int wm = (w & 1) * 64, wn = (w >> 1) * 64;
    const int col = lane & 15, quad = lane >> 4;
    const int r0 = tid >> 2, c0 = (tid & 3) * 8;

    const f32x4 zero = {0.f, 0.f, 0.f, 0.f};
    f32x4 acc[4][4];
#pragma unroll
    for (int i = 0; i < 4; i++)
#pragma unroll
        for (int j = 0; j < 4; j++) acc[i][j] = zero;

    for (int k0 = 0; k0 < K; k0 += 32) {
        __syncthreads();
        *(int4*)&As[r0 * LDSW + c0]        = *(const int4*)&A[(size_t)(m0 + r0) * K + k0 + c0];
        *(int4*)&As[(r0 + 64) * LDSW + c0] = *(const int4*)&A[(size_t)(m0 + r0 + 64) * K + k0 + c0];
        *(int4*)&Bs[r0 * LDSW + c0]        = *(const int4*)&W[(size_t)(n0 + r0) * K + k0 + c0];
        *(int4*)&Bs[(r0 + 64) * LDSW + c0] = *(const int4*)&W[(size_t)(n0 + r0 + 64) * K + k0 + c0];
        __syncthreads();
        short8 af[4], bf[4];
#pragma unroll
        for (int mt = 0; mt < 4; mt++)
            af[mt] = *(const short8*)&As[(wm + mt * 16 + col) * LDSW + quad * 8];
#pragma unroll
        for (int nt = 0; nt < 4; nt++)
            bf[nt] = *(const short8*)&Bs[(wn + nt * 16 + col) * LDSW + quad * 8];
#pragma unroll
        for (int mt = 0; mt < 4; mt++)
#pragma unroll
            for (int nt = 0; nt < 4; nt++)
                acc[mt][nt] = __builtin_amdgcn_mfma_f32_16x16x32_bf16(af[mt], bf[nt], acc[mt][nt], 0, 0, 0);
    }

#pragma unroll
    for (int mt = 0; mt < 4; mt++) {
#pragma unroll
        for (int nt = 0; nt < 4; nt++) {
            const int n = n0 + wn + nt * 16 + col;
            const float bv = bias[n];
#pragma unroll
            for (int r = 0; r < 4; r++) {
                const int m = m0 + wm + mt * 16 + quad * 4 + r;
                const float v = acc[mt][nt][r] + bv;
                if constexpr (MODE == 2) {
                    ((float*)outp)[(size_t)m * N + n] = v;
                } else if constexpr (MODE == 0) {
                    const int b = m >> 11, t = m & 2047, h = n >> 6, dh = n & 63;
                    ((unsigned short*)outp)[(((size_t)(b * N_HEADS + h)) * SEQ_T + t) * HEAD_DIM + dh] = f2bf(v);
                } else {
                    const int b = m >> 11, t = m & 2047, h = n >> 6, dh = n & 63;
                    ((unsigned short*)outp)[((size_t)(b * N_HEADS + h) * HEAD_DIM + dh) * SEQ_T + t] = f2bf(v);
                }
            }
        }
    }
}

// ---------------- flash attention ----------------
// Q,K: [BH, T, Dh] bf16 ; Vt: [BH, Dh, T] bf16 ; Y: [B*T, D_MODEL] bf16 at [b,t,h,dh]
__global__ __launch_bounds__(256, 2) void flash_attn(
    const unsigned short* __restrict__ Q,
    const unsigned short* __restrict__ Kk,
    const unsigned short* __restrict__ Vt,
    unsigned short* __restrict__ Y)
{
    __shared__ unsigned short Ks[64 * 72];
    __shared__ unsigned short Vs[64 * 72];
    __shared__ unsigned short Ps[4 * 16 * 72];
    const int qblk = blockIdx.x & 31;        // T/64 = 32 q-tiles
    const int bh = blockIdx.x >> 5;
    const int b = bh >> 4, h = bh & 15;
    const int tid = threadIdx.x;
    const int w = tid >> 6, lane = tid & 63;
    const int col = lane & 15, quad = lane >> 4;
    const int qrow = qblk * 64 + w * 16;     // this wave's 16-row strip

    const unsigned short* qp = Q + ((size_t)bh * SEQ_T + qrow + col) * HEAD_DIM;
    short8 qf0 = *(const short8*)&qp[quad * 8];
    short8 qf1 = *(const short8*)&qp[quad * 8 + 32];

    const unsigned short* kp = Kk + (size_t)bh * SEQ_T * HEAD_DIM;
    const unsigned short* vp = Vt + (size_t)bh * HEAD_DIM * SEQ_T;

    const f32x4 zero = {0.f, 0.f, 0.f, 0.f};
    f32x4 acc[4];
#pragma unroll
    for (int nt = 0; nt < 4; nt++) acc[nt] = zero;
    float mrow[4] = {-__builtin_inff(), -__builtin_inff(), -__builtin_inff(), -__builtin_inff()};
    float lrow[4] = {0.f, 0.f, 0.f, 0.f};

    const int sr = tid >> 3, sc = (tid & 7) * 8;  // staging: 32 rows per half, 8 chunks/row
    unsigned short* pw = &Ps[w * 16 * 72];

    for (int kt = 0; kt <= qblk; kt++) {
        const int kb = kt * 64;
        __syncthreads();
        *(int4*)&Ks[sr * 72 + sc]        = *(const int4*)&kp[(size_t)(kb + sr) * HEAD_DIM + sc];
        *(int4*)&Ks[(sr + 32) * 72 + sc] = *(const int4*)&kp[(size_t)(kb + sr + 32) * HEAD_DIM + sc];
        *(int4*)&Vs[sr * 72 + sc]        = *(const int4*)&vp[(size_t)sr * SEQ_T + kb + sc];
        *(int4*)&Vs[(sr + 32) * 72 + sc] = *(const int4*)&vp[(size_t)(sr + 32) * SEQ_T + kb + sc];
        __syncthreads();

        f32x4 s[4];
#pragma unroll
        for (int nt = 0; nt < 4; nt++) {
            short8 kf0 = *(const short8*)&Ks[(nt * 16 + col) * 72 + quad * 8];
            short8 kf1 = *(const short8*)&Ks[(nt * 16 + col) * 72 + quad * 8 + 32];
            f32x4 z = zero;
            z = __builtin_amdgcn_mfma_f32_16x16x32_bf16(qf0, kf0, z, 0, 0, 0);
            z = __builtin_amdgcn_mfma_f32_16x16x32_bf16(qf1, kf1, z, 0, 0, 0);
            s[nt] = z;
        }

        const bool diag = (kt == qblk);
        float tmax[4] = {-__builtin_inff(), -__builtin_inff(), -__builtin_inff(), -__builtin_inff()};
#pragma unroll
        for (int nt = 0; nt < 4; nt++)
#pragma unroll
            for (int r = 0; r < 4; r++) {
                float v = s[nt][r] * 0.125f;
                if (diag && (kb + nt * 16 + col) > (qrow + quad * 4 + r)) v = -__builtin_inff();
                s[nt][r] = v;
                tmax[r] = fmaxf(tmax[r], v);
            }
#pragma unroll
        for (int r = 0; r < 4; r++) {
            tmax[r] = fmaxf(tmax[r], __shfl_xor(tmax[r], 1));
            tmax[r] = fmaxf(tmax[r], __shfl_xor(tmax[r], 2));
            tmax[r] = fmaxf(tmax[r], __shfl_xor(tmax[r], 4));
            tmax[r] = fmaxf(tmax[r], __shfl_xor(tmax[r], 8));
        }
#pragma unroll
        for (int r = 0; r < 4; r++) {
            const float mnew = fmaxf(mrow[r], tmax[r]);
            const float alpha = __expf(mrow[r] - mnew);
            mrow[r] = mnew;
            float rs = 0.f;
#pragma unroll
            for (int nt = 0; nt < 4; nt++) {
                const float p = __expf(s[nt][r] - mnew);
                s[nt][r] = p;
                rs += p;
            }
            rs += __shfl_xor(rs, 1);
            rs += __shfl_xor(rs, 2);
            rs += __shfl_xor(rs, 4);
            rs += __shfl_xor(rs, 8);
            lrow[r] = lrow[r] * alpha + rs;
#pragma unroll
            for (int nt = 0; nt < 4; nt++) acc[nt][r] *= alpha;
        }

        // P: C-layout -> LDS -> A-layout
#pragma unroll
        for (int nt = 0; nt < 4; nt++)
#pragma unroll
            for (int r = 0; r < 4; r++)
                pw[(quad * 4 + r) * 72 + nt * 16 + col] = f2bf(s[nt][r]);
        asm volatile("s_waitcnt lgkmcnt(0)" ::: "memory");
        short8 pf0 = *(const short8*)&pw[col * 72 + quad * 8];
        short8 pf1 = *(const short8*)&pw[col * 72 + quad * 8 + 32];
#pragma unroll
        for (int nt = 0; nt < 4; nt++) {
            short8 vf0 = *(const short8*)&Vs[(nt * 16 + col) * 72 + quad * 8];
            short8 vf1 = *(const short8*)&Vs[(nt * 16 + col) * 72 + quad * 8 + 32];
            acc[nt] = __builtin_amdgcn_mfma_f32_16x16x32_bf16(pf0, vf0, acc[nt], 0, 0, 0);
            acc[nt] = __builtin_amdgcn_mfma_f32_16x16x32_bf16(pf1, vf1, acc[nt], 0, 0, 0);
        }
    }

#pragma unroll
    for (int nt = 0; nt < 4; nt++)
#pragma unroll
        for (int r = 0; r < 4; r++) {
            const int qg = qrow + quad * 4 + r;
            const float v = acc[nt][r] / lrow[r];
            Y[((size_t)(b * SEQ_T + qg)) * D_MODEL + h * HEAD_DIM + nt * 16 + col] = f2bf(v);
        }
}

extern "C" void kernel_launch(void* const* d_in, const int* in_sizes, int n_in,
                              void* d_out, int out_size, void* d_ws, size_t ws_size,
                              hipStream_t stream) {
    const float* x  = (const float*)d_in[0];
    const float* Wq = (const float*)d_in[1];
    const float* bq = (const float*)d_in[2];
    const float* Wk = (const float*)d_in[3];
    const float* bk = (const float*)d_in[4];
    const float* Wv = (const float*)d_in[5];
    const float* bv = (const float*)d_in[6];
    const float* Wp = (const float*)d_in[7];
    const float* bp = (const float*)d_in[8];
    float* out = (float*)d_out;

    char* ws = (char*)d_ws;
    const size_t XSZ = (size_t)4096 * 1024 * 2;   // x bf16
    const size_t WSZ = (size_t)1024 * 1024 * 2;   // weight bf16
    unsigned short* xb  = (unsigned short*)ws;  ws += XSZ;
    unsigned short* wqb = (unsigned short*)ws;  ws += WSZ;
    unsigned short* wkb = (unsigned short*)ws;  ws += WSZ;
    unsigned short* wvb = (unsigned short*)ws;  ws += WSZ;
    unsigned short* wpb = (unsigned short*)ws;  ws += WSZ;
    unsigned short* qb  = (unsigned short*)ws;  ws += XSZ;  // [BH,T,Dh]
    unsigned short* kb  = (unsigned short*)ws;  ws += XSZ;  // [BH,T,Dh]
    unsigned short* vtb = (unsigned short*)ws;  ws += XSZ;  // [BH,Dh,T]
    unsigned short* yb  = (unsigned short*)ws;  ws += XSZ;  // [B*T, D]

    cvt_bf16<<<4096, 256, 0, stream>>>(x, xb, 1048576);
    cvt_bf16<<<1024, 256, 0, stream>>>(Wq, wqb, 262144);
    cvt_bf16<<<1024, 256, 0, stream>>>(Wk, wkb, 262144);
    cvt_bf16<<<1024, 256, 0, stream>>>(Wv, wvb, 262144);
    cvt_bf16<<<1024, 256, 0, stream>>>(Wp, wpb, 262144);

    dim3 g(8, 32);
    gemm_bt<0><<<g, 256, 0, stream>>>(xb, wqb, bq, qb);
    gemm_bt<0><<<g, 256, 0, stream>>>(xb, wkb, bk, kb);
    gemm_bt<1><<<g, 256, 0, stream>>>(xb, wvb, bv, vtb);

    flash_attn<<<1024, 256, 0, stream>>>(qb, kb, vtb, yb);

    gemm_bt<2><<<g, 256, 0, stream>>>(yb, wpb, bp, out);
}

// Round 2
// 270.554 us; speedup vs baseline: 1.1608x; 1.1608x over previous
//
#include <hip/hip_runtime.h>
#include <math.h>

#define D_MODEL 1024
#define N_HEADS 16
#define HEAD_DIM 64
#define SEQ_T 2048
#define BATCH 2

typedef __attribute__((ext_vector_type(8))) short short8;
typedef __attribute__((ext_vector_type(4))) float f32x4;

__device__ __forceinline__ unsigned short f2bf(float f) {
    union { float f; unsigned int u; } v; v.f = f;
    return (unsigned short)((v.u + 0x7FFFu + ((v.u >> 16) & 1u)) >> 16);
}

__device__ __forceinline__ void glds16(const unsigned short* g, unsigned short* l) {
    __builtin_amdgcn_global_load_lds(
        (const __attribute__((address_space(1))) unsigned int*)g,
        (__attribute__((address_space(3))) unsigned int*)l, 16, 0, 0);
}

// ---------------- fused fp32 -> bf16 convert (x + 4 weights) ----------------
__global__ void cvt_all(const float4* __restrict__ x,
                        const float4* __restrict__ Wq, const float4* __restrict__ Wk,
                        const float4* __restrict__ Wv, const float4* __restrict__ Wp,
                        ushort4* __restrict__ xb, ushort4* __restrict__ wb,
                        ushort4* __restrict__ wpb) {
    int i = blockIdx.x * 256 + threadIdx.x;
    float4 v; ushort4* dst;
    if (i < 1048576) { v = x[i]; dst = xb + i; }
    else {
        int j = i - 1048576;
        int wsel = j >> 18;          // 262144 float4 per weight
        int o = j & 262143;
        const float4* s = wsel == 0 ? Wq : wsel == 1 ? Wk : wsel == 2 ? Wv : Wp;
        v = s[o];
        dst = (wsel == 3) ? (wpb + o) : (wb + (size_t)wsel * 262144 + o);
    }
    ushort4 u;
    u.x = f2bf(v.x); u.y = f2bf(v.y); u.z = f2bf(v.z); u.w = f2bf(v.w);
    *dst = u;
}

// ---------------- GEMM: C = A[M,K] * W[N,K]^T + bias (m97 structure) ----------------
// MODE 2: fp32 out row-major [M,1024] (final projection), bias b0
// MODE 3: fused QKV: N=3072; n<1024 -> q [B,H,T,Dh], <2048 -> k, else v [B,H,Dh,T]
template<int MODE, int MTILE>
__global__ __launch_bounds__(256) void gemm2(
    const unsigned short* __restrict__ A,
    const unsigned short* __restrict__ W,
    const float* __restrict__ b0, const float* __restrict__ b1, const float* __restrict__ b2,
    void* __restrict__ o0, void* __restrict__ o1, void* __restrict__ o2)
{
    constexpr int K = 1024;
    constexpr int MT = MTILE / 32;          // m-frags per wave (4 or 2)
    constexpr int CAW = MTILE / 64;         // A-chunks per wave (2 or 1)
    __shared__ unsigned short As[MTILE * 32];  // unpadded, row-major [MTILE][32]
    __shared__ unsigned short Bs[128 * 32];
    const int m0 = blockIdx.y * MTILE;
    const int n0 = blockIdx.x * 128;
    const int tid = threadIdx.x;
    const int w = tid >> 6, lane = tid & 63;
    const int col = lane & 15, quad = lane >> 4;
    const int wm = (w & 1) * (MTILE / 2), wn = (w >> 1) * 64;
    const int lr = lane >> 2, lc = (lane & 3) * 8;   // staging: 4 lanes/row, 8 shorts each

    const f32x4 zero = {0.f, 0.f, 0.f, 0.f};
    f32x4 acc[MT][4];
#pragma unroll
    for (int i = 0; i < MT; i++)
#pragma unroll
        for (int j = 0; j < 4; j++) acc[i][j] = zero;

    for (int k0 = 0; k0 < K; k0 += 32) {
        __syncthreads();
#pragma unroll
        for (int c = 0; c < CAW; c++) {
            const int q = w * CAW + c;
            glds16(&A[(size_t)(m0 + q * 16 + lr) * K + k0 + lc], &As[q * 512]);
        }
#pragma unroll
        for (int c = 0; c < 2; c++) {
            const int q = w * 2 + c;
            glds16(&W[(size_t)(n0 + q * 16 + lr) * K + k0 + lc], &Bs[q * 512]);
        }
        __syncthreads();
        short8 af[MT], bf[4];
#pragma unroll
        for (int mt = 0; mt < MT; mt++)
            af[mt] = *(const short8*)&As[(wm + mt * 16 + col) * 32 + quad * 8];
#pragma unroll
        for (int nt = 0; nt < 4; nt++)
            bf[nt] = *(const short8*)&Bs[(wn + nt * 16 + col) * 32 + quad * 8];
#pragma unroll
        for (int mt = 0; mt < MT; mt++)
#pragma unroll
            for (int nt = 0; nt < 4; nt++)
                acc[mt][nt] = __builtin_amdgcn_mfma_f32_16x16x32_bf16(af[mt], bf[nt], acc[mt][nt], 0, 0, 0);
    }

#pragma unroll
    for (int mt = 0; mt < MT; mt++) {
#pragma unroll
        for (int nt = 0; nt < 4; nt++) {
            const int n = n0 + wn + nt * 16 + col;
            float bias;
            if constexpr (MODE == 2) bias = b0[n];
            else {
                const int sel = n >> 10, nq = n & 1023;
                bias = (sel == 0 ? b0 : sel == 1 ? b1 : b2)[nq];
            }
#pragma unroll
            for (int r = 0; r < 4; r++) {
                const int m = m0 + wm + mt * 16 + quad * 4 + r;
                const float v = acc[mt][nt][r] + bias;
                if constexpr (MODE == 2) {
                    ((float*)o0)[(size_t)m * 1024 + n] = v;
                } else {
                    const int sel = n >> 10, nq = n & 1023;
                    const int h = nq >> 6, dh = nq & 63, b = m >> 11, t = m & 2047;
                    if (sel < 2) {
                        unsigned short* dst = sel ? (unsigned short*)o1 : (unsigned short*)o0;
                        dst[(((size_t)(b * N_HEADS + h)) * SEQ_T + t) * HEAD_DIM + dh] = f2bf(v);
                    } else {
                        ((unsigned short*)o2)[((size_t)(b * N_HEADS + h) * HEAD_DIM + dh) * SEQ_T + t] = f2bf(v);
                    }
                }
            }
        }
    }
}

// ---------------- barrier-free flash attention ----------------
// Q,K: [BH,T,Dh] bf16 ; Vt: [BH,Dh,T] bf16 ; Y: [B*T, D_MODEL] bf16
// Each wave owns a 16-row Q strip; processes pair (s, 127-s) for uniform work.
// K/V fragments loaded directly from global (L2-resident, XCD-swizzled).
__global__ __launch_bounds__(256) void flash2(
    const unsigned short* __restrict__ Q,
    const unsigned short* __restrict__ Kk,
    const unsigned short* __restrict__ Vt,
    unsigned short* __restrict__ Y)
{
    __shared__ unsigned short Ps[4 * 16 * 72];
    const int tid = threadIdx.x;
    const int w = tid >> 6, lane = tid & 63;
    const int col = lane & 15, quad = lane >> 4;
    const int i = blockIdx.x;
    const int xcd = i & 7, j = i >> 3;
    const int bh = xcd * 4 + (j & 3);        // 4 heads per XCD class -> L2 locality
    const int pair = (j >> 2) * 4 + w;       // 0..63
    const int b = bh >> 4, h = bh & 15;

    const unsigned short* qbase = Q + (size_t)bh * SEQ_T * HEAD_DIM;
    const unsigned short* kbase = Kk + (size_t)bh * SEQ_T * HEAD_DIM;
    const unsigned short* vbase = Vt + (size_t)bh * HEAD_DIM * SEQ_T;
    unsigned short* pw = &Ps[w * 16 * 72];

    const float CS = 0.125f * 1.44269504088896f;  // scale * log2(e)
    const f32x4 zero = {0.f, 0.f, 0.f, 0.f};

    for (int ti = 0; ti < 2; ti++) {
        const int s = ti ? (127 - pair) : pair;
        const int qrow = s * 16;
        const short8 qf0 = *(const short8*)&qbase[(size_t)(qrow + col) * HEAD_DIM + quad * 8];
        const short8 qf1 = *(const short8*)&qbase[(size_t)(qrow + col) * HEAD_DIM + quad * 8 + 32];

        f32x4 acc[4];
#pragma unroll
        for (int nt = 0; nt < 4; nt++) acc[nt] = zero;
        float mrow[4] = {-__builtin_inff(), -__builtin_inff(), -__builtin_inff(), -__builtin_inff()};
        float lrow[4] = {0.f, 0.f, 0.f, 0.f};

        const int nk = (qrow + 79) >> 6;     // k-tiles of 64 needed for rows qrow..qrow+15
        for (int kt = 0; kt < nk; kt++) {
            const int kb = kt * 64;
            const unsigned short* kp = kbase + (size_t)kb * HEAD_DIM;
            short8 kf0[4], kf1[4], vf0[4], vf1[4];
#pragma unroll
            for (int nt = 0; nt < 4; nt++) {
                kf0[nt] = *(const short8*)&kp[(nt * 16 + col) * HEAD_DIM + quad * 8];
                kf1[nt] = *(const short8*)&kp[(nt * 16 + col) * HEAD_DIM + quad * 8 + 32];
                vf0[nt] = *(const short8*)&vbase[(size_t)(nt * 16 + col) * SEQ_T + kb + quad * 8];
                vf1[nt] = *(const short8*)&vbase[(size_t)(nt * 16 + col) * SEQ_T + kb + quad * 8 + 32];
            }
            f32x4 sv[4];
#pragma unroll
            for (int nt = 0; nt < 4; nt++) {
                f32x4 z = zero;
                z = __builtin_amdgcn_mfma_f32_16x16x32_bf16(qf0, kf0[nt], z, 0, 0, 0);
                z = __builtin_amdgcn_mfma_f32_16x16x32_bf16(qf1, kf1[nt], z, 0, 0, 0);
                sv[nt] = z;
            }

            const bool diag = (kt == nk - 1);
            float tmax[4] = {-__builtin_inff(), -__builtin_inff(), -__builtin_inff(), -__builtin_inff()};
#pragma unroll
            for (int nt = 0; nt < 4; nt++)
#pragma unroll
                for (int r = 0; r < 4; r++) {
                    float v = sv[nt][r] * CS;   // base-2 domain
                    if (diag && (kb + nt * 16 + col) > (qrow + quad * 4 + r)) v = -__builtin_inff();
                    sv[nt][r] = v;
                    tmax[r] = fmaxf(tmax[r], v);
                }
#pragma unroll
            for (int r = 0; r < 4; r++) {
                tmax[r] = fmaxf(tmax[r], __shfl_xor(tmax[r], 1));
                tmax[r] = fmaxf(tmax[r], __shfl_xor(tmax[r], 2));
                tmax[r] = fmaxf(tmax[r], __shfl_xor(tmax[r], 4));
                tmax[r] = fmaxf(tmax[r], __shfl_xor(tmax[r], 8));
            }
#pragma unroll
            for (int r = 0; r < 4; r++) {
                const float mnew = fmaxf(mrow[r], tmax[r]);
                const float alpha = exp2f(mrow[r] - mnew);
                mrow[r] = mnew;
                float rs = 0.f;
#pragma unroll
                for (int nt = 0; nt < 4; nt++) {
                    const float p = exp2f(sv[nt][r] - mnew);
                    sv[nt][r] = p;
                    rs += p;
                }
                rs += __shfl_xor(rs, 1);
                rs += __shfl_xor(rs, 2);
                rs += __shfl_xor(rs, 4);
                rs += __shfl_xor(rs, 8);
                lrow[r] = lrow[r] * alpha + rs;
#pragma unroll
                for (int nt = 0; nt < 4; nt++) acc[nt][r] *= alpha;
            }

            // P: C-layout -> per-wave LDS -> A-layout (no barrier: private region, in-order DS)
#pragma unroll
            for (int nt = 0; nt < 4; nt++)
#pragma unroll
                for (int r = 0; r < 4; r++)
                    pw[(quad * 4 + r) * 72 + nt * 16 + col] = f2bf(sv[nt][r]);
            asm volatile("s_waitcnt lgkmcnt(0)" ::: "memory");
            const short8 pf0 = *(const short8*)&pw[col * 72 + quad * 8];
            const short8 pf1 = *(const short8*)&pw[col * 72 + quad * 8 + 32];
#pragma unroll
            for (int nt = 0; nt < 4; nt++) {
                acc[nt] = __builtin_amdgcn_mfma_f32_16x16x32_bf16(pf0, vf0[nt], acc[nt], 0, 0, 0);
                acc[nt] = __builtin_amdgcn_mfma_f32_16x16x32_bf16(pf1, vf1[nt], acc[nt], 0, 0, 0);
            }
        }

#pragma unroll
        for (int nt = 0; nt < 4; nt++)
#pragma unroll
            for (int r = 0; r < 4; r++) {
                const int qg = qrow + quad * 4 + r;
                const float v = acc[nt][r] / lrow[r];
                Y[((size_t)(b * SEQ_T + qg)) * D_MODEL + h * HEAD_DIM + nt * 16 + col] = f2bf(v);
            }
    }
}

extern "C" void kernel_launch(void* const* d_in, const int* in_sizes, int n_in,
                              void* d_out, int out_size, void* d_ws, size_t ws_size,
                              hipStream_t stream) {
    const float* x  = (const float*)d_in[0];
    const float* Wq = (const float*)d_in[1];
    const float* bq = (const float*)d_in[2];
    const float* Wk = (const float*)d_in[3];
    const float* bk = (const float*)d_in[4];
    const float* Wv = (const float*)d_in[5];
    const float* bv = (const float*)d_in[6];
    const float* Wp = (const float*)d_in[7];
    const float* bp = (const float*)d_in[8];
    float* out = (float*)d_out;

    char* ws = (char*)d_ws;
    const size_t XSZ = (size_t)4096 * 1024 * 2;       // 8 MB
    unsigned short* xb  = (unsigned short*)ws;  ws += XSZ;
    unsigned short* wb  = (unsigned short*)ws;  ws += (size_t)3072 * 1024 * 2;  // [Wq;Wk;Wv]
    unsigned short* wpb = (unsigned short*)ws;  ws += (size_t)1024 * 1024 * 2;
    unsigned short* qb  = (unsigned short*)ws;  ws += XSZ;  // [BH,T,Dh]
    unsigned short* kb  = (unsigned short*)ws;  ws += XSZ;  // [BH,T,Dh]
    unsigned short* vtb = (unsigned short*)ws;  ws += XSZ;  // [BH,Dh,T]
    unsigned short* yb  = (unsigned short*)ws;  ws += XSZ;  // [B*T, D]

    cvt_all<<<8192, 256, 0, stream>>>((const float4*)x, (const float4*)Wq, (const float4*)Wk,
                                      (const float4*)Wv, (const float4*)Wp,
                                      (ushort4*)xb, (ushort4*)wb, (ushort4*)wpb);

    gemm2<3, 128><<<dim3(24, 32), 256, 0, stream>>>(xb, wb, bq, bk, bv, qb, kb, vtb);

    flash2<<<512, 256, 0, stream>>>(qb, kb, vtb, yb);

    gemm2<2, 64><<<dim3(8, 64), 256, 0, stream>>>(yb, wpb, bp, nullptr, nullptr, out, nullptr, nullptr);
}

// Round 4
// 269.512 us; speedup vs baseline: 1.1653x; 1.0039x over previous
//
#include <hip/hip_runtime.h>
#include <math.h>

#define D_MODEL 1024
#define N_HEADS 16
#define HEAD_DIM 64
#define SEQ_T 2048
#define BATCH 2

typedef __attribute__((ext_vector_type(8))) short short8;
typedef __attribute__((ext_vector_type(4))) float f32x4;

__device__ __forceinline__ unsigned short f2bf(float f) {
    union { float f; unsigned int u; } v; v.f = f;
    return (unsigned short)((v.u + 0x7FFFu + ((v.u >> 16) & 1u)) >> 16);
}

__device__ __forceinline__ void glds16(const unsigned short* g, unsigned short* l) {
    __builtin_amdgcn_global_load_lds(
        (const __attribute__((address_space(1))) unsigned int*)g,
        (__attribute__((address_space(3))) unsigned int*)l, 16, 0, 0);
}

// ---------------- fused fp32 -> bf16 convert (x + 4 weights) ----------------
__global__ void cvt_all(const float4* __restrict__ x,
                        const float4* __restrict__ Wq, const float4* __restrict__ Wk,
                        const float4* __restrict__ Wv, const float4* __restrict__ Wp,
                        ushort4* __restrict__ xb, ushort4* __restrict__ wb,
                        ushort4* __restrict__ wpb) {
    int i = blockIdx.x * 256 + threadIdx.x;
    float4 v; ushort4* dst;
    if (i < 1048576) { v = x[i]; dst = xb + i; }
    else {
        int j = i - 1048576;
        int wsel = j >> 18;
        int o = j & 262143;
        const float4* s = wsel == 0 ? Wq : wsel == 1 ? Wk : wsel == 2 ? Wv : Wp;
        v = s[o];
        dst = (wsel == 3) ? (wpb + o) : (wb + (size_t)wsel * 262144 + o);
    }
    ushort4 u;
    u.x = f2bf(v.x); u.y = f2bf(v.y); u.z = f2bf(v.z); u.w = f2bf(v.w);
    *dst = u;
}

// ---------------- GEMM: C = A[M,K] * W[N,K]^T + bias (m97 structure) ----------------
// MODE 2: fp32 out row-major [M,1024], bias b0
// MODE 3: fused QKV: N=3072; q [B,H,T,Dh]; k [B,H,Tperm,Dh] (32-key permuted); v [B,H,Dh,T]
template<int MODE, int MTILE>
__global__ __launch_bounds__(256) void gemm2(
    const unsigned short* __restrict__ A,
    const unsigned short* __restrict__ W,
    const float* __restrict__ b0, const float* __restrict__ b1, const float* __restrict__ b2,
    void* __restrict__ o0, void* __restrict__ o1, void* __restrict__ o2)
{
    constexpr int K = 1024;
    constexpr int MT = MTILE / 32;
    constexpr int CAW = MTILE / 64;
    __shared__ unsigned short As[MTILE * 32];
    __shared__ unsigned short Bs[128 * 32];
    const int m0 = blockIdx.y * MTILE;
    const int n0 = blockIdx.x * 128;
    const int tid = threadIdx.x;
    const int w = tid >> 6, lane = tid & 63;
    const int col = lane & 15, quad = lane >> 4;
    const int wm = (w & 1) * (MTILE / 2), wn = (w >> 1) * 64;
    const int lr = lane >> 2, lc = (lane & 3) * 8;

    const f32x4 zero = {0.f, 0.f, 0.f, 0.f};
    f32x4 acc[MT][4];
#pragma unroll
    for (int i = 0; i < MT; i++)
#pragma unroll
        for (int j = 0; j < 4; j++) acc[i][j] = zero;

    for (int k0 = 0; k0 < K; k0 += 32) {
        __syncthreads();
#pragma unroll
        for (int c = 0; c < CAW; c++) {
            const int q = w * CAW + c;
            glds16(&A[(size_t)(m0 + q * 16 + lr) * K + k0 + lc], &As[q * 512]);
        }
#pragma unroll
        for (int c = 0; c < 2; c++) {
            const int q = w * 2 + c;
            glds16(&W[(size_t)(n0 + q * 16 + lr) * K + k0 + lc], &Bs[q * 512]);
        }
        __syncthreads();
        short8 af[MT], bf[4];
#pragma unroll
        for (int mt = 0; mt < MT; mt++)
            af[mt] = *(const short8*)&As[(wm + mt * 16 + col) * 32 + quad * 8];
#pragma unroll
        for (int nt = 0; nt < 4; nt++)
            bf[nt] = *(const short8*)&Bs[(wn + nt * 16 + col) * 32 + quad * 8];
#pragma unroll
        for (int mt = 0; mt < MT; mt++)
#pragma unroll
            for (int nt = 0; nt < 4; nt++)
                acc[mt][nt] = __builtin_amdgcn_mfma_f32_16x16x32_bf16(af[mt], bf[nt], acc[mt][nt], 0, 0, 0);
    }

#pragma unroll
    for (int mt = 0; mt < MT; mt++) {
#pragma unroll
        for (int nt = 0; nt < 4; nt++) {
            const int n = n0 + wn + nt * 16 + col;
            float bias;
            if constexpr (MODE == 2) bias = b0[n];
            else {
                const int sel = n >> 10, nq = n & 1023;
                bias = (sel == 0 ? b0 : sel == 1 ? b1 : b2)[nq];
            }
#pragma unroll
            for (int r = 0; r < 4; r++) {
                const int m = m0 + wm + mt * 16 + quad * 4 + r;
                const float v = acc[mt][nt][r] + bias;
                if constexpr (MODE == 2) {
                    ((float*)o0)[(size_t)m * 1024 + n] = v;
                } else {
                    const int sel = n >> 10, nq = n & 1023;
                    const int h = nq >> 6, dh = nq & 63, b = m >> 11, t = m & 2047;
                    if (sel < 2) {
                        unsigned short* dst = sel ? (unsigned short*)o1 : (unsigned short*)o0;
                        int tt = t;
                        if (sel == 1) {
                            // K permutation: pos (t16*16 + q*4 + r) <- key (q*8 + t16*4 + r)
                            const int tb = t & 31;
                            tt = (t & ~31) + ((tb & 4) << 2) + ((tb >> 3) << 2) + (tb & 3);
                        }
                        dst[(((size_t)(b * N_HEADS + h)) * SEQ_T + tt) * HEAD_DIM + dh] = f2bf(v);
                    } else {
                        ((unsigned short*)o2)[((size_t)(b * N_HEADS + h) * HEAD_DIM + dh) * SEQ_T + t] = f2bf(v);
                    }
                }
            }
        }
    }
}

// ---------------- flash attention: transposed scores, permuted keys, zero LDS ----------------
// Q: [BH,T,Dh] ; Kp: [BH,Tperm,Dh] (32-key permuted) ; Vt: [BH,Dh,T] ; Y: [B*T,D_MODEL]
// St = K*Q^T (swapped operands). Lane holds St[key][query=col]; after 2 St tiles per
// 32-key group, packed exp'd scores ARE the 16x16x32 A-operand (k=quad*8+j). No LDS.
__global__ __launch_bounds__(256) void flash4(
    const unsigned short* __restrict__ Q,
    const unsigned short* __restrict__ Kp,
    const unsigned short* __restrict__ Vt,
    unsigned short* __restrict__ Y)
{
    const int tid = threadIdx.x;
    const int w = tid >> 6, lane = tid & 63;
    const int col = lane & 15, quad = lane >> 4;
    const int i = blockIdx.x;
    const int xcd = i & 7, j = i >> 3;
    const int bh = xcd * 4 + (j & 3);        // L2 locality: 4 heads per XCD class
    const int pair = (j >> 2) * 4 + w;       // 0..63
    const int b = bh >> 4, h = bh & 15;

    const unsigned short* qbase = Q + (size_t)bh * SEQ_T * HEAD_DIM;
    const unsigned short* kbase = Kp + (size_t)bh * SEQ_T * HEAD_DIM;
    const unsigned short* vbase = Vt + (size_t)bh * HEAD_DIM * SEQ_T;

    const float CS = 0.125f * 1.44269504088896f;  // scale * log2(e)
    const float NEGINF = -__builtin_inff();
    const f32x4 zero = {0.f, 0.f, 0.f, 0.f};

    for (int ti = 0; ti < 2; ti++) {
        const int s = ti ? (127 - pair) : pair;   // balanced pair: 33-34 iters total
        const int qrow = s * 16;
        const short8 qf0 = *(const short8*)&qbase[(size_t)(qrow + col) * HEAD_DIM + quad * 8];
        const short8 qf1 = *(const short8*)&qbase[(size_t)(qrow + col) * HEAD_DIM + quad * 8 + 32];

        f32x4 acc[4];
#pragma unroll
        for (int nt = 0; nt < 4; nt++) acc[nt] = zero;
        float m = NEGINF, l = 0.f;

        const int nk = (qrow + 79) >> 6;
        for (int kt = 0; kt < nk; kt++) {
            const int kb = kt * 64;

            // V B-frags: B[k=quad*8+j][n=col], contiguous 16B loads
            short8 vB[2][4];
#pragma unroll
            for (int g = 0; g < 2; g++)
#pragma unroll
                for (int nt = 0; nt < 4; nt++)
                    vB[g][nt] = *(const short8*)&vbase[(size_t)(nt * 16 + col) * SEQ_T + kb + g * 32 + quad * 8];

            // St = K*Q^T over 4 16-key tiles (permuted storage rows)
            const unsigned short* kp = kbase + (size_t)kb * HEAD_DIM;
            f32x4 St[4];
#pragma unroll
            for (int kc = 0; kc < 4; kc++) {
                const short8 kf0 = *(const short8*)&kp[(kc * 16 + col) * HEAD_DIM + quad * 8];
                const short8 kf1 = *(const short8*)&kp[(kc * 16 + col) * HEAD_DIM + quad * 8 + 32];
                f32x4 z = zero;
                z = __builtin_amdgcn_mfma_f32_16x16x32_bf16(kf0, qf0, z, 0, 0, 0);
                z = __builtin_amdgcn_mfma_f32_16x16x32_bf16(kf1, qf1, z, 0, 0, 0);
                St[kc] = z;
            }

            // scale + causal mask + per-lane max (16 keys/lane)
            // actual key of St[kc][r] = kb + (kc>>1)*32 + quad*8 + (kc&1)*4 + r
            const bool diag = (kt == nk - 1);
            float vmax = NEGINF;
#pragma unroll
            for (int kc = 0; kc < 4; kc++) {
                const int kbase_c = kb + (kc >> 1) * 32 + quad * 8 + (kc & 1) * 4;
#pragma unroll
                for (int r = 0; r < 4; r++) {
                    float v = St[kc][r] * CS;
                    if (diag && (kbase_c + r > qrow + col)) v = NEGINF;
                    St[kc][r] = v;
                    vmax = fmaxf(vmax, v);
                }
            }
            vmax = fmaxf(vmax, __shfl_xor(vmax, 16));
            vmax = fmaxf(vmax, __shfl_xor(vmax, 32));

            const float mnew = fmaxf(m, vmax);
            const float alpha = exp2f(m - mnew);
            m = mnew;

            // exp + pack: group g A-frag = [St[2g] r0..3 | St[2g+1] r0..3] (k=quad*8+j)
            float ps = 0.f;
            short8 pA[2];
#pragma unroll
            for (int g = 0; g < 2; g++) {
#pragma unroll
                for (int t16 = 0; t16 < 2; t16++) {
                    const int kc = 2 * g + t16;
#pragma unroll
                    for (int r = 0; r < 4; r++) {
                        const float p = exp2f(St[kc][r] - mnew);
                        ps += p;
                        pA[g][t16 * 4 + r] = (short)f2bf(p);
                    }
                }
            }
            ps += __shfl_xor(ps, 16);
            ps += __shfl_xor(ps, 32);
            l = l * alpha + ps;

            // alpha indexed by query=col; acc rows are query=quad*4+r
            float ar[4];
#pragma unroll
            for (int r = 0; r < 4; r++) ar[r] = __shfl(alpha, quad * 4 + r);
#pragma unroll
            for (int nt = 0; nt < 4; nt++)
#pragma unroll
                for (int r = 0; r < 4; r++) acc[nt][r] *= ar[r];

#pragma unroll
            for (int g = 0; g < 2; g++)
#pragma unroll
                for (int nt = 0; nt < 4; nt++)
                    acc[nt] = __builtin_amdgcn_mfma_f32_16x16x32_bf16(pA[g], vB[g][nt], acc[nt], 0, 0, 0);
        }

        const float linv = 1.0f / l;
        float lr[4];
#pragma unroll
        for (int r = 0; r < 4; r++) lr[r] = __shfl(linv, quad * 4 + r);
#pragma unroll
        for (int nt = 0; nt < 4; nt++)
#pragma unroll
            for (int r = 0; r < 4; r++) {
                const int qg = qrow + quad * 4 + r;
                Y[((size_t)(b * SEQ_T + qg)) * D_MODEL + h * HEAD_DIM + nt * 16 + col] = f2bf(acc[nt][r] * lr[r]);
            }
    }
}

extern "C" void kernel_launch(void* const* d_in, const int* in_sizes, int n_in,
                              void* d_out, int out_size, void* d_ws, size_t ws_size,
                              hipStream_t stream) {
    const float* x  = (const float*)d_in[0];
    const float* Wq = (const float*)d_in[1];
    const float* bq = (const float*)d_in[2];
    const float* Wk = (const float*)d_in[3];
    const float* bk = (const float*)d_in[4];
    const float* Wv = (const float*)d_in[5];
    const float* bv = (const float*)d_in[6];
    const float* Wp = (const float*)d_in[7];
    const float* bp = (const float*)d_in[8];
    float* out = (float*)d_out;

    char* ws = (char*)d_ws;
    const size_t XSZ = (size_t)4096 * 1024 * 2;
    unsigned short* xb  = (unsigned short*)ws;  ws += XSZ;
    unsigned short* wb  = (unsigned short*)ws;  ws += (size_t)3072 * 1024 * 2;
    unsigned short* wpb = (unsigned short*)ws;  ws += (size_t)1024 * 1024 * 2;
    unsigned short* qb  = (unsigned short*)ws;  ws += XSZ;
    unsigned short* kb  = (unsigned short*)ws;  ws += XSZ;  // permuted keys
    unsigned short* vtb = (unsigned short*)ws;  ws += XSZ;
    unsigned short* yb  = (unsigned short*)ws;  ws += XSZ;

    cvt_all<<<8192, 256, 0, stream>>>((const float4*)x, (const float4*)Wq, (const float4*)Wk,
                                      (const float4*)Wv, (const float4*)Wp,
                                      (ushort4*)xb, (ushort4*)wb, (ushort4*)wpb);

    gemm2<3, 128><<<dim3(24, 32), 256, 0, stream>>>(xb, wb, bq, bk, bv, qb, kb, vtb);

    flash4<<<512, 256, 0, stream>>>(qb, kb, vtb, yb);

    gemm2<2, 64><<<dim3(8, 64), 256, 0, stream>>>(yb, wpb, bp, nullptr, nullptr, out, nullptr, nullptr);
}